// Round 1
// baseline (121.824 us; speedup 1.0000x reference)
//
#include <hip/hip_runtime.h>
#include <hip/hip_bf16.h>

#define B_ 16
#define P_ 4096
#define A_ 32
#define V_ 778
#define BLOCK 256
#define NPTS (B_ * P_)

__global__ void zero_out_kernel(float* out) {
    out[0] = 0.0f;
    out[1] = 0.0f;
}

__global__ __launch_bounds__(BLOCK) void dual_hoi_loss_kernel(
    const float* __restrict__ verts,          // (B, V, 3)
    const float* __restrict__ anchors,        // (B, A, 3)
    const float* __restrict__ choir,          // (B, P, 6)
    const float* __restrict__ hand_contacts,  // (B, P)
    const float* __restrict__ bps_mean,       // (B, 1, 3)
    const float* __restrict__ bps_scalar,     // (1,)
    const float* __restrict__ bps_basis,      // (P, 3)
    float* __restrict__ out)                  // [choir_loss, hand_contact_loss]
{
    __shared__ float4 sv[V_];

    const int tid = threadIdx.x;
    const int gid = blockIdx.x * BLOCK + tid;
    const int b = gid >> 12;        // gid / P_   (P_ = 4096)
    const int p = gid & (P_ - 1);   // gid % P_

    // Stage this batch's verts into LDS as padded float4 (12448 B).
    const float* vb = verts + b * (V_ * 3);
    for (int j = tid; j < V_; j += BLOCK) {
        sv[j] = make_float4(vb[3 * j], vb[3 * j + 1], vb[3 * j + 2], 0.0f);
    }
    __syncthreads();

    // Decode target point: (basis + delta) / scalar + mean
    const float inv_s = 1.0f / bps_scalar[0];
    const float* c = choir + (size_t)gid * 6;
    const float c1 = c[1], c2 = c[2], c3 = c[3], c4 = c[4], c5 = c[5];
    const float mx = bps_mean[3 * b], my = bps_mean[3 * b + 1], mz = bps_mean[3 * b + 2];
    const float tx = (bps_basis[3 * p]     + c1) * inv_s + mx;
    const float ty = (bps_basis[3 * p + 1] + c2) * inv_s + my;
    const float tz = (bps_basis[3 * p + 2] + c3) * inv_s + mz;

    // --- choir loss term: distance to the single indexed anchor ---
    const int idx = (int)c5;
    const float* an = anchors + ((size_t)b * A_ + idx) * 3;
    const float ax = tx - an[0], ay = ty - an[1], az = tz - an[2];
    const float d2a = fmaf(ax, ax, fmaf(ay, ay, az * az));
    const float dsel = sqrtf(fmaxf(d2a, 1e-12f));
    const float e1 = dsel - c4;
    float s1 = e1 * e1;

    // --- contact loss term: min squared distance over verts ---
    float mind2 = 3.402823466e38f;
    #pragma unroll 4
    for (int j = 0; j < V_; ++j) {
        const float4 v = sv[j];
        const float dx = tx - v.x;
        const float dy = ty - v.y;
        const float dz = tz - v.z;
        const float d2 = fmaf(dx, dx, fmaf(dy, dy, dz * dz));
        mind2 = fminf(mind2, d2);
    }
    mind2 = fmaxf(mind2, 1e-12f);           // == min_d^2 after sqrt-clamp in ref
    const float contact = expf(-100.0f * mind2);
    const float e2 = hand_contacts[gid] - contact;
    float s2 = e2 * e2;

    // --- block reduction: wave shuffle then cross-wave via LDS ---
    for (int off = 32; off > 0; off >>= 1) {
        s1 += __shfl_down(s1, off);
        s2 += __shfl_down(s2, off);
    }
    __shared__ float red[8];
    const int wave = tid >> 6;
    if ((tid & 63) == 0) { red[wave] = s1; red[4 + wave] = s2; }
    __syncthreads();
    if (tid == 0) {
        const float t1 = red[0] + red[1] + red[2] + red[3];
        const float t2 = red[4] + red[5] + red[6] + red[7];
        atomicAdd(&out[0], t1 * (1.0f / NPTS));
        atomicAdd(&out[1], t2 * (1.0f / NPTS));
    }
}

extern "C" void kernel_launch(void* const* d_in, const int* in_sizes, int n_in,
                              void* d_out, int out_size, void* d_ws, size_t ws_size,
                              hipStream_t stream) {
    const float* verts         = (const float*)d_in[0];
    const float* anchors       = (const float*)d_in[1];
    const float* choir         = (const float*)d_in[2];
    const float* hand_contacts = (const float*)d_in[3];
    const float* bps_mean      = (const float*)d_in[4];
    const float* bps_scalar    = (const float*)d_in[5];
    const float* bps_basis     = (const float*)d_in[6];
    float* out = (float*)d_out;

    zero_out_kernel<<<1, 1, 0, stream>>>(out);
    dual_hoi_loss_kernel<<<NPTS / BLOCK, BLOCK, 0, stream>>>(
        verts, anchors, choir, hand_contacts, bps_mean, bps_scalar, bps_basis, out);
}

// Round 2
// 93.888 us; speedup vs baseline: 1.2975x; 1.2975x over previous
//
#include <hip/hip_runtime.h>
#include <hip/hip_bf16.h>

#define B_ 16
#define P_ 4096
#define A_ 32
#define V_ 778
#define NPTS (B_ * P_)

#define SPLIT 8          // lanes cooperating per point
#define CH 98            // ceil(778/8) verts per lane
#define VP (SPLIT * CH)  // 784, padded vert count
#define BLOCK 256
#define PTS_PER_BLOCK (BLOCK / SPLIT)          // 32
#define NBLOCKS (NPTS / PTS_PER_BLOCK)         // 2048
#define BLOCKS_PER_B (P_ / PTS_PER_BLOCK)      // 128

__global__ __launch_bounds__(BLOCK) void dual_hoi_main_kernel(
    const float* __restrict__ verts,          // (B, V, 3)
    const float* __restrict__ anchors,        // (B, A, 3)
    const float* __restrict__ choir,          // (B, P, 6)
    const float* __restrict__ hand_contacts,  // (B, P)
    const float* __restrict__ bps_mean,       // (B, 1, 3)
    const float* __restrict__ bps_scalar,     // (1,)
    const float* __restrict__ bps_basis,      // (P, 3)
    float2* __restrict__ partials)            // (NBLOCKS,) {s_choir, s_contact}
{
    __shared__ float4 sv[VP];

    const int tid = threadIdx.x;
    const int bid = blockIdx.x;
    const int b = bid / BLOCKS_PER_B;                        // batch
    const int pbase = (bid % BLOCKS_PER_B) * PTS_PER_BLOCK;  // first point
    const int plocal = tid >> 3;                             // 0..31
    const int chunk = tid & (SPLIT - 1);                     // 0..7
    const int p = pbase + plocal;
    const int gid = (b << 12) + p;

    // Stage this batch's verts into LDS (padded float4; pads pushed far away).
    const float* vb = verts + b * (V_ * 3);
    for (int j = tid; j < VP; j += BLOCK) {
        sv[j] = (j < V_)
              ? make_float4(vb[3 * j], vb[3 * j + 1], vb[3 * j + 2], 0.0f)
              : make_float4(1e18f, 1e18f, 1e18f, 0.0f);
    }
    __syncthreads();

    // Decode target point (all 8 lanes of a point compute the same t).
    const float inv_s = 1.0f / bps_scalar[0];
    const float* c = choir + (size_t)gid * 6;
    const float c1 = c[1], c2 = c[2], c3 = c[3];
    const float tx = (bps_basis[3 * p]     + c1) * inv_s + bps_mean[3 * b];
    const float ty = (bps_basis[3 * p + 1] + c2) * inv_s + bps_mean[3 * b + 1];
    const float tz = (bps_basis[3 * p + 2] + c3) * inv_s + bps_mean[3 * b + 2];

    // Min squared distance over this lane's vert chunk (2 chains for ILP).
    const float4* pv = sv + chunk * CH;
    float m0 = 1e30f, m1 = 1e30f;
    #pragma unroll 7
    for (int j = 0; j < CH; j += 2) {
        const float4 v0 = pv[j];
        const float4 v1 = pv[j + 1];
        const float dx0 = tx - v0.x, dy0 = ty - v0.y, dz0 = tz - v0.z;
        m0 = fminf(m0, fmaf(dx0, dx0, fmaf(dy0, dy0, dz0 * dz0)));
        const float dx1 = tx - v1.x, dy1 = ty - v1.y, dz1 = tz - v1.z;
        m1 = fminf(m1, fmaf(dx1, dx1, fmaf(dy1, dy1, dz1 * dz1)));
    }
    float m = fminf(m0, m1);
    // Min-reduce across the 8 lanes of this point.
    m = fminf(m, __shfl_xor(m, 1));
    m = fminf(m, __shfl_xor(m, 2));
    m = fminf(m, __shfl_xor(m, 4));

    float s1 = 0.0f, s2 = 0.0f;
    if (chunk == 0) {
        // contact term
        const float mind2 = fmaxf(m, 1e-12f);
        const float contact = expf(-100.0f * mind2);
        const float e2 = hand_contacts[gid] - contact;
        s2 = e2 * e2;
        // choir term: distance to the single indexed anchor
        const int idx = (int)c[5];
        const float* an = anchors + ((size_t)b * A_ + idx) * 3;
        const float ax = tx - an[0], ay = ty - an[1], az = tz - an[2];
        const float dsel = sqrtf(fmaxf(fmaf(ax, ax, fmaf(ay, ay, az * az)), 1e-12f));
        const float e1 = dsel - c[4];
        s1 = e1 * e1;
    }

    // Block reduction: full-wave shuffle then cross-wave via LDS.
    for (int off = 32; off > 0; off >>= 1) {
        s1 += __shfl_down(s1, off);
        s2 += __shfl_down(s2, off);
    }
    __shared__ float red[8];
    const int wave = tid >> 6;
    if ((tid & 63) == 0) { red[wave] = s1; red[4 + wave] = s2; }
    __syncthreads();
    if (tid == 0) {
        partials[bid] = make_float2(red[0] + red[1] + red[2] + red[3],
                                    red[4] + red[5] + red[6] + red[7]);
    }
}

__global__ __launch_bounds__(BLOCK) void dual_hoi_reduce_kernel(
    const float2* __restrict__ partials, float* __restrict__ out)
{
    const int tid = threadIdx.x;
    float s1 = 0.0f, s2 = 0.0f;
    #pragma unroll
    for (int i = tid; i < NBLOCKS; i += BLOCK) {
        const float2 v = partials[i];
        s1 += v.x;
        s2 += v.y;
    }
    for (int off = 32; off > 0; off >>= 1) {
        s1 += __shfl_down(s1, off);
        s2 += __shfl_down(s2, off);
    }
    __shared__ float red[8];
    const int wave = tid >> 6;
    if ((tid & 63) == 0) { red[wave] = s1; red[4 + wave] = s2; }
    __syncthreads();
    if (tid == 0) {
        out[0] = (red[0] + red[1] + red[2] + red[3]) * (1.0f / NPTS);
        out[1] = (red[4] + red[5] + red[6] + red[7]) * (1.0f / NPTS);
    }
}

extern "C" void kernel_launch(void* const* d_in, const int* in_sizes, int n_in,
                              void* d_out, int out_size, void* d_ws, size_t ws_size,
                              hipStream_t stream) {
    const float* verts         = (const float*)d_in[0];
    const float* anchors       = (const float*)d_in[1];
    const float* choir         = (const float*)d_in[2];
    const float* hand_contacts = (const float*)d_in[3];
    const float* bps_mean      = (const float*)d_in[4];
    const float* bps_scalar    = (const float*)d_in[5];
    const float* bps_basis     = (const float*)d_in[6];
    float* out = (float*)d_out;
    float2* partials = (float2*)d_ws;   // NBLOCKS * 8 bytes = 16 KB

    dual_hoi_main_kernel<<<NBLOCKS, BLOCK, 0, stream>>>(
        verts, anchors, choir, hand_contacts, bps_mean, bps_scalar, bps_basis,
        partials);
    dual_hoi_reduce_kernel<<<1, BLOCK, 0, stream>>>(partials, out);
}

// Round 4
// 78.343 us; speedup vs baseline: 1.5550x; 1.1984x over previous
//
#include <hip/hip_runtime.h>
#include <hip/hip_bf16.h>

#define B_ 16
#define P_ 4096
#define A_ 32
#define V_ 778
#define NPTS (B_ * P_)

#define SPLIT 16                         // lanes cooperating per point
#define K 4                              // points per thread
#define CH 51                            // padded verts per lane (16*51=816>=778)
#define VP (SPLIT * CH)                  // 816
#define BLOCK 256
#define PTS_PER_BLOCK ((BLOCK / SPLIT) * K)    // 64
#define NBLOCKS (NPTS / PTS_PER_BLOCK)         // 1024
#define BLOCKS_PER_B (P_ / PTS_PER_BLOCK)      // 64

__global__ __launch_bounds__(BLOCK, 4) void dual_hoi_main_kernel(
    const float* __restrict__ verts,          // (B, V, 3)
    const float* __restrict__ anchors,        // (B, A, 3)
    const float* __restrict__ choir,          // (B, P, 6)
    const float* __restrict__ hand_contacts,  // (B, P)
    const float* __restrict__ bps_mean,       // (B, 1, 3)
    const float* __restrict__ bps_scalar,     // (1,)
    const float* __restrict__ bps_basis,      // (P, 3)
    float2* __restrict__ partials)            // (NBLOCKS,) {s_choir, s_contact}
{
    __shared__ float4 sv[VP];               // 13056 B

    const int tid = threadIdx.x;
    const int bid = blockIdx.x;
    const int b = bid / BLOCKS_PER_B;
    const int pbase = (bid % BLOCKS_PER_B) * PTS_PER_BLOCK;
    const int plocal = tid >> 4;            // 0..15 point-slot
    const int chunk = tid & (SPLIT - 1);    // 0..15 vert-chunk

    // Stage this batch's verts into LDS (padded float4; pads far away).
    const float* vb = verts + b * (V_ * 3);
    for (int j = tid; j < VP; j += BLOCK) {
        sv[j] = (j < V_)
              ? make_float4(vb[3 * j], vb[3 * j + 1], vb[3 * j + 2], 0.0f)
              : make_float4(1e18f, 1e18f, 1e18f, 0.0f);
    }
    __syncthreads();

    const float inv_s = 1.0f / bps_scalar[0];
    const float mx = bps_mean[3 * b], my = bps_mean[3 * b + 1], mz = bps_mean[3 * b + 2];

    // Decode K target points per thread (16 lanes of a point share identical t).
    float tx[K], ty[K], tz[K];
    int pq[K];
    #pragma unroll
    for (int q = 0; q < K; ++q) {
        const int p = pbase + plocal + 16 * q;
        pq[q] = p;
        const int gid = (b << 12) + p;
        const float* c = choir + (size_t)gid * 6;
        tx[q] = (bps_basis[3 * p]     + c[1]) * inv_s + mx;
        ty[q] = (bps_basis[3 * p + 1] + c[2]) * inv_s + my;
        tz[q] = (bps_basis[3 * p + 2] + c[3]) * inv_s + mz;
    }

    // Min squared distance: each vert load amortized over K points.
    const float4* pv = sv + chunk * CH;
    float mn[K] = {1e30f, 1e30f, 1e30f, 1e30f};
    #pragma unroll 3
    for (int j = 0; j < CH; ++j) {
        const float4 v = pv[j];
        #pragma unroll
        for (int q = 0; q < K; ++q) {
            const float dx = tx[q] - v.x;
            const float dy = ty[q] - v.y;
            const float dz = tz[q] - v.z;
            mn[q] = fminf(mn[q], fmaf(dx, dx, fmaf(dy, dy, dz * dz)));
        }
    }
    // Min-reduce across the 16 lanes of each point.
    #pragma unroll
    for (int q = 0; q < K; ++q) {
        mn[q] = fminf(mn[q], __shfl_xor(mn[q], 1));
        mn[q] = fminf(mn[q], __shfl_xor(mn[q], 2));
        mn[q] = fminf(mn[q], __shfl_xor(mn[q], 4));
        mn[q] = fminf(mn[q], __shfl_xor(mn[q], 8));
    }

    float s1 = 0.0f, s2 = 0.0f;
    if (chunk == 0) {
        #pragma unroll
        for (int q = 0; q < K; ++q) {
            const int gid = (b << 12) + pq[q];
            const float* c = choir + (size_t)gid * 6;
            // contact term
            const float mind2 = fmaxf(mn[q], 1e-12f);
            const float contact = expf(-100.0f * mind2);
            const float e2 = hand_contacts[gid] - contact;
            s2 += e2 * e2;
            // choir term: distance to the single indexed anchor
            const int idx = (int)c[5];
            const float* an = anchors + ((size_t)b * A_ + idx) * 3;
            const float ax = tx[q] - an[0], ay = ty[q] - an[1], az = tz[q] - an[2];
            const float dsel = sqrtf(fmaxf(fmaf(ax, ax, fmaf(ay, ay, az * az)), 1e-12f));
            const float e1 = dsel - c[4];
            s1 += e1 * e1;
        }
    }

    // Block reduction: full-wave shuffle then cross-wave via LDS.
    for (int off = 32; off > 0; off >>= 1) {
        s1 += __shfl_down(s1, off);
        s2 += __shfl_down(s2, off);
    }
    __shared__ float red[8];
    const int wave = tid >> 6;
    if ((tid & 63) == 0) { red[wave] = s1; red[4 + wave] = s2; }
    __syncthreads();
    if (tid == 0) {
        partials[bid] = make_float2(red[0] + red[1] + red[2] + red[3],
                                    red[4] + red[5] + red[6] + red[7]);
    }
}

__global__ __launch_bounds__(BLOCK) void dual_hoi_reduce_kernel(
    const float2* __restrict__ partials, float* __restrict__ out)
{
    const int tid = threadIdx.x;
    float s1 = 0.0f, s2 = 0.0f;
    #pragma unroll
    for (int i = tid; i < NBLOCKS; i += BLOCK) {
        const float2 v = partials[i];
        s1 += v.x;
        s2 += v.y;
    }
    for (int off = 32; off > 0; off >>= 1) {
        s1 += __shfl_down(s1, off);
        s2 += __shfl_down(s2, off);
    }
    __shared__ float red[8];
    const int wave = tid >> 6;
    if ((tid & 63) == 0) { red[wave] = s1; red[4 + wave] = s2; }
    __syncthreads();
    if (tid == 0) {
        out[0] = (red[0] + red[1] + red[2] + red[3]) * (1.0f / NPTS);
        out[1] = (red[4] + red[5] + red[6] + red[7]) * (1.0f / NPTS);
    }
}

extern "C" void kernel_launch(void* const* d_in, const int* in_sizes, int n_in,
                              void* d_out, int out_size, void* d_ws, size_t ws_size,
                              hipStream_t stream) {
    const float* verts         = (const float*)d_in[0];
    const float* anchors       = (const float*)d_in[1];
    const float* choir         = (const float*)d_in[2];
    const float* hand_contacts = (const float*)d_in[3];
    const float* bps_mean      = (const float*)d_in[4];
    const float* bps_scalar    = (const float*)d_in[5];
    const float* bps_basis     = (const float*)d_in[6];
    float* out = (float*)d_out;
    float2* partials = (float2*)d_ws;   // NBLOCKS * 8 bytes = 8 KB

    dual_hoi_main_kernel<<<NBLOCKS, BLOCK, 0, stream>>>(
        verts, anchors, choir, hand_contacts, bps_mean, bps_scalar, bps_basis,
        partials);
    dual_hoi_reduce_kernel<<<1, BLOCK, 0, stream>>>(partials, out);
}

// Round 5
// 75.797 us; speedup vs baseline: 1.6072x; 1.0336x over previous
//
#include <hip/hip_runtime.h>
#include <hip/hip_bf16.h>

#define B_ 16
#define P_ 4096
#define A_ 32
#define V_ 778
#define NPTS (B_ * P_)

#define SPLIT 16                         // lanes cooperating per point
#define K 4                              // points per thread
#define CH 51                            // padded verts per lane (16*51=816>=778; 51 keeps 2-way banks)
#define VP (SPLIT * CH)                  // 816
#define BLOCK 256
#define PTS_PER_BLOCK ((BLOCK / SPLIT) * K)    // 64
#define NBLOCKS (NPTS / PTS_PER_BLOCK)         // 1024
#define BLOCKS_PER_B (P_ / PTS_PER_BLOCK)      // 64

__global__ __launch_bounds__(BLOCK, 4) void dual_hoi_main_kernel(
    const float* __restrict__ verts,          // (B, V, 3)
    const float* __restrict__ anchors,        // (B, A, 3)
    const float* __restrict__ choir,          // (B, P, 6)
    const float* __restrict__ hand_contacts,  // (B, P)
    const float* __restrict__ bps_mean,       // (B, 1, 3)
    const float* __restrict__ bps_scalar,     // (1,)
    const float* __restrict__ bps_basis,      // (P, 3)
    float2* __restrict__ partials)            // (NBLOCKS,) {s_choir, s_contact}
{
    __shared__ float4 sv[VP];               // 13056 B; w = 0.5*|v|^2

    const int tid = threadIdx.x;
    const int bid = blockIdx.x;
    const int b = bid / BLOCKS_PER_B;
    const int pbase = (bid % BLOCKS_PER_B) * PTS_PER_BLOCK;
    const int plocal = tid >> 4;            // 0..15 point-slot
    const int chunk = tid & (SPLIT - 1);    // 0..15 vert-chunk

    // Stage verts as (x, y, z, 0.5*|v|^2); pads get huge s so never selected.
    const float* vb = verts + b * (V_ * 3);
    for (int j = tid; j < VP; j += BLOCK) {
        if (j < V_) {
            const float x = vb[3 * j], y = vb[3 * j + 1], z = vb[3 * j + 2];
            sv[j] = make_float4(x, y, z, 0.5f * fmaf(x, x, fmaf(y, y, z * z)));
        } else {
            sv[j] = make_float4(0.0f, 0.0f, 0.0f, 1e30f);
        }
    }
    __syncthreads();

    const float inv_s = 1.0f / bps_scalar[0];
    const float mx = bps_mean[3 * b], my = bps_mean[3 * b + 1], mz = bps_mean[3 * b + 2];

    // Decode K target points per thread (16 lanes of a point share identical t).
    float tx[K], ty[K], tz[K];
    int pq[K];
    #pragma unroll
    for (int q = 0; q < K; ++q) {
        const int p = pbase + plocal + 16 * q;
        pq[q] = p;
        const int gid = (b << 12) + p;
        const float* c = choir + (size_t)gid * 6;
        tx[q] = (bps_basis[3 * p]     + c[1]) * inv_s + mx;
        ty[q] = (bps_basis[3 * p + 1] + c[2]) * inv_s + my;
        tz[q] = (bps_basis[3 * p + 2] + c[3]) * inv_s + mz;
    }

    // min over verts of s = 0.5|v|^2 - t.v  (same argmin as |t-v|^2).
    // 3 fma per pair; two verts per step -> v_min3 fusion.
    const float4* pv = sv + chunk * CH;
    float mn[K] = {1e30f, 1e30f, 1e30f, 1e30f};
    #pragma unroll 5
    for (int jj = 0; jj < (CH - 1) / 2; ++jj) {
        const float4 v0 = pv[2 * jj];
        const float4 v1 = pv[2 * jj + 1];
        #pragma unroll
        for (int q = 0; q < K; ++q) {
            const float s0 = fmaf(-tx[q], v0.x, fmaf(-ty[q], v0.y, fmaf(-tz[q], v0.z, v0.w)));
            const float s1 = fmaf(-tx[q], v1.x, fmaf(-ty[q], v1.y, fmaf(-tz[q], v1.z, v1.w)));
            mn[q] = fminf(mn[q], fminf(s0, s1));
        }
    }
    {   // tail vert j = CH-1
        const float4 v0 = pv[CH - 1];
        #pragma unroll
        for (int q = 0; q < K; ++q) {
            const float s0 = fmaf(-tx[q], v0.x, fmaf(-ty[q], v0.y, fmaf(-tz[q], v0.z, v0.w)));
            mn[q] = fminf(mn[q], s0);
        }
    }
    // Min-reduce across the 16 lanes of each point.
    #pragma unroll
    for (int q = 0; q < K; ++q) {
        mn[q] = fminf(mn[q], __shfl_xor(mn[q], 1));
        mn[q] = fminf(mn[q], __shfl_xor(mn[q], 2));
        mn[q] = fminf(mn[q], __shfl_xor(mn[q], 4));
        mn[q] = fminf(mn[q], __shfl_xor(mn[q], 8));
    }

    float s1 = 0.0f, s2 = 0.0f;
    if (chunk == 0) {
        #pragma unroll
        for (int q = 0; q < K; ++q) {
            const int gid = (b << 12) + pq[q];
            const float* c = choir + (size_t)gid * 6;
            // contact term: mind2 = |t|^2 + 2*s_min
            const float tn2 = fmaf(tx[q], tx[q], fmaf(ty[q], ty[q], tz[q] * tz[q]));
            const float mind2 = fmaxf(fmaf(2.0f, mn[q], tn2), 1e-12f);
            const float contact = expf(-100.0f * mind2);
            const float e2 = hand_contacts[gid] - contact;
            s2 += e2 * e2;
            // choir term: exact direct distance to the single indexed anchor
            const int idx = (int)c[5];
            const float* an = anchors + ((size_t)b * A_ + idx) * 3;
            const float ax = tx[q] - an[0], ay = ty[q] - an[1], az = tz[q] - an[2];
            const float dsel = sqrtf(fmaxf(fmaf(ax, ax, fmaf(ay, ay, az * az)), 1e-12f));
            const float e1 = dsel - c[4];
            s1 += e1 * e1;
        }
    }

    // Block reduction: full-wave shuffle then cross-wave via LDS.
    for (int off = 32; off > 0; off >>= 1) {
        s1 += __shfl_down(s1, off);
        s2 += __shfl_down(s2, off);
    }
    __shared__ float red[8];
    const int wave = tid >> 6;
    if ((tid & 63) == 0) { red[wave] = s1; red[4 + wave] = s2; }
    __syncthreads();
    if (tid == 0) {
        partials[bid] = make_float2(red[0] + red[1] + red[2] + red[3],
                                    red[4] + red[5] + red[6] + red[7]);
    }
}

__global__ __launch_bounds__(BLOCK) void dual_hoi_reduce_kernel(
    const float2* __restrict__ partials, float* __restrict__ out)
{
    const int tid = threadIdx.x;
    float s1 = 0.0f, s2 = 0.0f;
    #pragma unroll
    for (int i = tid; i < NBLOCKS; i += BLOCK) {
        const float2 v = partials[i];
        s1 += v.x;
        s2 += v.y;
    }
    for (int off = 32; off > 0; off >>= 1) {
        s1 += __shfl_down(s1, off);
        s2 += __shfl_down(s2, off);
    }
    __shared__ float red[8];
    const int wave = tid >> 6;
    if ((tid & 63) == 0) { red[wave] = s1; red[4 + wave] = s2; }
    __syncthreads();
    if (tid == 0) {
        out[0] = (red[0] + red[1] + red[2] + red[3]) * (1.0f / NPTS);
        out[1] = (red[4] + red[5] + red[6] + red[7]) * (1.0f / NPTS);
    }
}

extern "C" void kernel_launch(void* const* d_in, const int* in_sizes, int n_in,
                              void* d_out, int out_size, void* d_ws, size_t ws_size,
                              hipStream_t stream) {
    const float* verts         = (const float*)d_in[0];
    const float* anchors       = (const float*)d_in[1];
    const float* choir         = (const float*)d_in[2];
    const float* hand_contacts = (const float*)d_in[3];
    const float* bps_mean      = (const float*)d_in[4];
    const float* bps_scalar    = (const float*)d_in[5];
    const float* bps_basis     = (const float*)d_in[6];
    float* out = (float*)d_out;
    float2* partials = (float2*)d_ws;   // NBLOCKS * 8 bytes = 8 KB

    dual_hoi_main_kernel<<<NBLOCKS, BLOCK, 0, stream>>>(
        verts, anchors, choir, hand_contacts, bps_mean, bps_scalar, bps_basis,
        partials);
    dual_hoi_reduce_kernel<<<1, BLOCK, 0, stream>>>(partials, out);
}